// Round 9
// baseline (94.187 us; speedup 1.0000x reference)
//
#include <hip/hip_runtime.h>
#include <hip/hip_bf16.h>
#include <stdint.h>

#define M_DIM 8192
#define N_DIM 2048
#define K_DIM 2048
#define NT    (K_DIM / 32)   // 64 K-tiles of BK=32

typedef float f32x4 __attribute__((ext_vector_type(4)));
typedef short bf16x8 __attribute__((ext_vector_type(8)));

typedef const __attribute__((address_space(1))) char* gp_t;
typedef __attribute__((address_space(3))) char* lp_t;

static __device__ __forceinline__ void gload_lds16(const void* g, void* l) {
  __builtin_amdgcn_global_load_lds((gp_t)(uintptr_t)g, (lp_t)(uint32_t)(uintptr_t)l, 16, 0, 0);
}

// round-to-nearest-even f32 -> bf16 bits (exact for -1, 0, +1)
static __device__ __forceinline__ unsigned short f2bf(float f) {
  unsigned int u = __float_as_uint(f);
  unsigned int r = (u + 0x7FFFu + ((u >> 16) & 1u)) >> 16;
  return (unsigned short)r;
}

// ---------------- fused: x -> bf16 (blocks 0..16383) + |W| partials (blocks 16384..17407) ----
__global__ void cvt_x_absum(const float* __restrict__ x, unsigned short* __restrict__ xb,
                            const float* __restrict__ w, float* __restrict__ partials) {
  const int b = blockIdx.x;
  if (b < 16384) {
    int tid = b * 256 + threadIdx.x;
    float4 v = ((const float4*)x)[tid];
    ushort4 o;
    o.x = f2bf(v.x); o.y = f2bf(v.y); o.z = f2bf(v.z); o.w = f2bf(v.w);
    ((ushort4*)xb)[tid] = o;
  } else {
    int tid = (b - 16384) * 256 + threadIdx.x;
    const float4* w4 = (const float4*)w;
    float s = 0.f;
#pragma unroll
    for (int i = 0; i < 4; ++i) {
      float4 v = w4[tid + i * 262144];
      s += fabsf(v.x) + fabsf(v.y) + fabsf(v.z) + fabsf(v.w);
    }
#pragma unroll
    for (int off = 32; off > 0; off >>= 1) s += __shfl_down(s, off, 64);
    __shared__ float ls[4];
    if ((threadIdx.x & 63) == 0) ls[threadIdx.x >> 6] = s;
    __syncthreads();
    if (threadIdx.x == 0) partials[b - 16384] = (ls[0] + ls[1]) + (ls[2] + ls[3]);
  }
}

// ---------------- W -> ternary bf16 {-1,0,1}; each block self-reduces scale ----------------
__global__ void quant_w(const float* __restrict__ w, const float* __restrict__ partials,
                        unsigned short* __restrict__ wt, float* __restrict__ scale_out) {
  __shared__ float ls[4];
  float s = 0.f;
#pragma unroll
  for (int i = 0; i < 4; ++i) s += partials[threadIdx.x + i * 256];
#pragma unroll
  for (int off = 32; off > 0; off >>= 1) s += __shfl_down(s, off, 64);
  if ((threadIdx.x & 63) == 0) ls[threadIdx.x >> 6] = s;
  __syncthreads();
  const float scale = ((ls[0] + ls[1]) + (ls[2] + ls[3])) * (1.0f / 4194304.0f);
  if (blockIdx.x == 0 && threadIdx.x == 0) scale_out[0] = scale;

  const float inv = 1.0f / (scale + 1e-10f);
  int tid = blockIdx.x * 256 + threadIdx.x;
  float4 v = ((const float4*)w)[tid];
  ushort4 o;
  float t;
  t = fminf(1.f, fmaxf(-1.f, rintf(v.x * inv))); o.x = f2bf(t);
  t = fminf(1.f, fmaxf(-1.f, rintf(v.y * inv))); o.y = f2bf(t);
  t = fminf(1.f, fmaxf(-1.f, rintf(v.z * inv))); o.z = f2bf(t);
  t = fminf(1.f, fmaxf(-1.f, rintf(v.w * inv))); o.w = f2bf(t);
  ((ushort4*)wt)[tid] = o;
}

// ---------------- 256x256 GEMM, 4-buffer BK=32 stream ----------------
// 8 waves (2Mx4N), 512 thr. LDS = 4 bufs x 32KB (A 16KB + B 16KB). Staging runs 3 tiles
// ahead via gload_lds; vmcnt(8) per tile drains loads issued ~3 tiles earlier (no wait);
// ONE barrier/tile (protects buf[t&3] from tile t+4's stage -> 4 tiles of slack).
// 2-bit XOR swizzle for 64B rows: byte ^= (row&3)<<4 (bijective; wave's 64 lanes cover a
// contiguous 1KB -> conflict-free). 12 ds_read_b128 + 4 gloads + 32 MFMA per tile.

#define VMCNT(n) asm volatile("s_waitcnt vmcnt(" #n ")" ::: "memory")
#define FENCE    asm volatile("" ::: "memory")
#define BARRIER  do { FENCE; __builtin_amdgcn_s_barrier(); FENCE; } while (0)

// stage half-tiles (8KB each): linear LDS dest, inverse-swizzled global source
#define SA(bufsel, r) gload_lds16(Ag + offA[r] + ktA, ldsb + (bufsel) * 32768 + tid * 16 + (r) * 8192)
#define SB(bufsel, r) gload_lds16(Bg + offB[r] + ktB, ldsb + (bufsel) * 32768 + 16384 + tid * 16 + (r) * 8192)

#define TILE_BODY(CB, STG, DO_STAGE, VM)                                                        \
  do {                                                                                          \
    const char* base = ldsb + (CB) * 32768;                                                     \
    bf16x8 af[8], bfr[4];                                                                       \
    if (DO_STAGE) { SA(STG, 0); SA(STG, 1); SB(STG, 0); SB(STG, 1); ktA += 64; ktB += 64; }     \
    _Pragma("unroll") for (int fr = 0; fr < 8; ++fr)                                            \
      af[fr] = *(const bf16x8*)(base + wr * 8192 + fr * 1024 + rdoff);                          \
    _Pragma("unroll") for (int fn = 0; fn < 4; ++fn)                                            \
      bfr[fn] = *(const bf16x8*)(base + 16384 + wc * 4096 + fn * 1024 + rdoff);                 \
    __builtin_amdgcn_s_setprio(1);                                                              \
    _Pragma("unroll") for (int fr = 0; fr < 8; ++fr)                                            \
      _Pragma("unroll") for (int fn = 0; fn < 4; ++fn)                                          \
        acc[fr][fn] = __builtin_amdgcn_mfma_f32_16x16x32_bf16(af[fr], bfr[fn],                  \
                                                              acc[fr][fn], 0, 0, 0);           \
    __builtin_amdgcn_s_setprio(0);                                                              \
    VM;                                                                                         \
    BARRIER;                                                                                    \
  } while (0)

__global__ void __launch_bounds__(512, 2)
gemm_bt(const unsigned short* __restrict__ A, const unsigned short* __restrict__ Bt,
        const float* __restrict__ bias, const float* __restrict__ scale_p,
        float* __restrict__ out) {
  __shared__ __align__(16) char lds_raw[131072];
  char* ldsb = (char*)lds_raw;

  const int tid = threadIdx.x;                 // 0..511
  const int lane = tid & 63;
  const int wid = tid >> 6;                    // 0..7
  const int wr = wid >> 2;                     // 0..1
  const int wc = wid & 3;                      // 0..3
  const int l15 = lane & 15, lhi = lane >> 4;

  // 2-bit read swizzle for 64B rows: byte ^= (row&3)<<4 ; row&3 == l15&3
  const int rdoff = l15 * 64 + ((lhi * 16) ^ ((l15 & 3) << 4));

  // XCD-aware swizzle: 256 blocks, 8 XCDs x 32-chunk; bm-major inside chunk
  const int bid = blockIdx.x;
  const int swz = (bid & 7) * 32 + (bid >> 3);
  const int bm = swz >> 3;                     // 0..31
  const int bn = swz & 7;                      // 0..7
  const int m0 = bm << 8, n0 = bn << 8;

  // staging: thread stages LDS row (tid>>2)+r*128, colbyte (tid&3)*16 (linear dest);
  // global source column inverse-swizzled so swizzled ds_reads see linear data.
  const int srow = tid >> 2;                                          // 0..127
  const int scol = (((tid & 3) ^ ((tid >> 2) & 3)) << 4);             // cb ^ (row&3)<<4
  const char* Ag = (const char*)A;
  const char* Bg = (const char*)Bt;
  uint32_t offA[2], offB[2];
#pragma unroll
  for (int r = 0; r < 2; ++r) {
    offA[r] = (uint32_t)(m0 + srow + r * 128) * (K_DIM * 2) + scol;
    offB[r] = (uint32_t)(n0 + srow + r * 128) * (K_DIM * 2) + scol;
  }
  uint32_t ktA = 0, ktB = 0;   // byte offset along K of next tile to stage (BK*2 = 64)

  f32x4 acc[8][4];
#pragma unroll
  for (int m = 0; m < 8; ++m)
#pragma unroll
    for (int n = 0; n < 4; ++n) {
      f32x4 z = {0.f, 0.f, 0.f, 0.f};
      acc[m][n] = z;
    }

  // ---- prologue: stage tiles 0,1,2 into buf0,1,2; drain tile 0 only (vmcnt 8)
  SA(0, 0); SA(0, 1); SB(0, 0); SB(0, 1); ktA = 64;  ktB = 64;
  SA(1, 0); SA(1, 1); SB(1, 0); SB(1, 1); ktA = 128; ktB = 128;
  SA(2, 0); SA(2, 1); SB(2, 0); SB(2, 1); ktA = 192; ktB = 192;
  VMCNT(8);
  BARRIER;

  // ---- main loop: t = 0..55 (14 x 4), all stage + vmcnt(8)
  for (int it = 0; it < 14; ++it) {
    TILE_BODY(0, 3, 1, VMCNT(8));
    TILE_BODY(1, 0, 1, VMCNT(8));
    TILE_BODY(2, 1, 1, VMCNT(8));
    TILE_BODY(3, 2, 1, VMCNT(8));
  }

  // ---- tail: t = 56..63 (stage while t <= NT-4; vmcnt 8 -> 4 -> 0)
  for (int t = 56; t < NT; ++t) {
    const int cb = t & 3;
    const int stg = (t + 3) & 3;
    const char* base = ldsb + cb * 32768;
    bf16x8 af[8], bfr[4];
    if (t <= NT - 4) { SA(stg, 0); SA(stg, 1); SB(stg, 0); SB(stg, 1); ktA += 64; ktB += 64; }
#pragma unroll
    for (int fr = 0; fr < 8; ++fr)
      af[fr] = *(const bf16x8*)(base + wr * 8192 + fr * 1024 + rdoff);
#pragma unroll
    for (int fn = 0; fn < 4; ++fn)
      bfr[fn] = *(const bf16x8*)(base + 16384 + wc * 4096 + fn * 1024 + rdoff);
    __builtin_amdgcn_s_setprio(1);
#pragma unroll
    for (int fr = 0; fr < 8; ++fr)
#pragma unroll
      for (int fn = 0; fn < 4; ++fn)
        acc[fr][fn] = __builtin_amdgcn_mfma_f32_16x16x32_bf16(af[fr], bfr[fn], acc[fr][fn], 0, 0, 0);
    __builtin_amdgcn_s_setprio(0);
    if (t <= NT - 4) { VMCNT(8); }
    else if (t == NT - 3) { VMCNT(4); }
    else { VMCNT(0); }
    BARRIER;
  }

  // ---- epilogue: C/D map col=lane&15, row=(lane>>4)*4+j ; fuse *scale + bias
  const float scale = scale_p[0];
#pragma unroll
  for (int n = 0; n < 4; ++n) {
    const int col = n0 + wc * 64 + n * 16 + l15;
    const float bv = bias[col];
#pragma unroll
    for (int m = 0; m < 8; ++m) {
      const int r0 = m0 + wr * 128 + m * 16 + lhi * 4;
      float* op = out + (size_t)r0 * N_DIM + col;
#pragma unroll
      for (int j = 0; j < 4; ++j) op[(size_t)j * N_DIM] = acc[m][n][j] * scale + bv;
    }
  }
}

extern "C" void kernel_launch(void* const* d_in, const int* in_sizes, int n_in,
                              void* d_out, int out_size, void* d_ws, size_t ws_size,
                              hipStream_t stream) {
  (void)in_sizes; (void)n_in; (void)out_size; (void)ws_size;
  const float* x    = (const float*)d_in[0];   // [4][2048][2048] f32
  const float* w    = (const float*)d_in[1];   // [2048][2048] f32
  const float* bias = (const float*)d_in[2];   // [2048] f32
  float* out = (float*)d_out;                  // [4][2048][2048] f32

  float* partials = (float*)d_ws;                              // 1024 f32
  float* scale_slot = partials + 1024;                         // 1 f32
  unsigned short* wt = (unsigned short*)((char*)d_ws + 8192);  // 8 MB bf16 W_t
  unsigned short* xb = (unsigned short*)((char*)d_ws + 8192 + (size_t)N_DIM * K_DIM * 2);  // 32 MB

  cvt_x_absum<<<17408, 256, 0, stream>>>(x, xb, w, partials);
  quant_w<<<4096, 256, 0, stream>>>(w, partials, wt, scale_slot);
  gemm_bt<<<256, 512, 0, stream>>>(xb, wt, bias, scale_slot, out);
}

// Round 10
// 93.731 us; speedup vs baseline: 1.0049x; 1.0049x over previous
//
#include <hip/hip_runtime.h>
#include <hip/hip_bf16.h>
#include <stdint.h>

#define M_DIM 8192
#define N_DIM 2048
#define K_DIM 2048
#define NT    (K_DIM / 64)   // 32 K-tiles of BK=64

typedef float f32x4 __attribute__((ext_vector_type(4)));
typedef float f32x16 __attribute__((ext_vector_type(16)));
typedef short bf16x8 __attribute__((ext_vector_type(8)));

typedef const __attribute__((address_space(1))) char* gp_t;
typedef __attribute__((address_space(3))) char* lp_t;

static __device__ __forceinline__ void gload_lds16(const void* g, void* l) {
  __builtin_amdgcn_global_load_lds((gp_t)(uintptr_t)g, (lp_t)(uint32_t)(uintptr_t)l, 16, 0, 0);
}

// round-to-nearest-even f32 -> bf16 bits (exact for -1, 0, +1)
static __device__ __forceinline__ unsigned short f2bf(float f) {
  unsigned int u = __float_as_uint(f);
  unsigned int r = (u + 0x7FFFu + ((u >> 16) & 1u)) >> 16;
  return (unsigned short)r;
}

// ---------------- fused: x -> bf16 (blocks 0..16383) + |W| partials (blocks 16384..17407) ----
__global__ void cvt_x_absum(const float* __restrict__ x, unsigned short* __restrict__ xb,
                            const float* __restrict__ w, float* __restrict__ partials) {
  const int b = blockIdx.x;
  if (b < 16384) {
    int tid = b * 256 + threadIdx.x;
    float4 v = ((const float4*)x)[tid];
    ushort4 o;
    o.x = f2bf(v.x); o.y = f2bf(v.y); o.z = f2bf(v.z); o.w = f2bf(v.w);
    ((ushort4*)xb)[tid] = o;
  } else {
    int tid = (b - 16384) * 256 + threadIdx.x;
    const float4* w4 = (const float4*)w;
    float s = 0.f;
#pragma unroll
    for (int i = 0; i < 4; ++i) {
      float4 v = w4[tid + i * 262144];
      s += fabsf(v.x) + fabsf(v.y) + fabsf(v.z) + fabsf(v.w);
    }
#pragma unroll
    for (int off = 32; off > 0; off >>= 1) s += __shfl_down(s, off, 64);
    __shared__ float ls[4];
    if ((threadIdx.x & 63) == 0) ls[threadIdx.x >> 6] = s;
    __syncthreads();
    if (threadIdx.x == 0) partials[b - 16384] = (ls[0] + ls[1]) + (ls[2] + ls[3]);
  }
}

// ---------------- W -> ternary bf16 {-1,0,1}; each block self-reduces scale ----------------
__global__ void quant_w(const float* __restrict__ w, const float* __restrict__ partials,
                        unsigned short* __restrict__ wt, float* __restrict__ scale_out) {
  __shared__ float ls[4];
  float s = 0.f;
#pragma unroll
  for (int i = 0; i < 4; ++i) s += partials[threadIdx.x + i * 256];
#pragma unroll
  for (int off = 32; off > 0; off >>= 1) s += __shfl_down(s, off, 64);
  if ((threadIdx.x & 63) == 0) ls[threadIdx.x >> 6] = s;
  __syncthreads();
  const float scale = ((ls[0] + ls[1]) + (ls[2] + ls[3])) * (1.0f / 4194304.0f);
  if (blockIdx.x == 0 && threadIdx.x == 0) scale_out[0] = scale;

  const float inv = 1.0f / (scale + 1e-10f);
  int tid = blockIdx.x * 256 + threadIdx.x;
  float4 v = ((const float4*)w)[tid];
  ushort4 o;
  float t;
  t = fminf(1.f, fmaxf(-1.f, rintf(v.x * inv))); o.x = f2bf(t);
  t = fminf(1.f, fmaxf(-1.f, rintf(v.y * inv))); o.y = f2bf(t);
  t = fminf(1.f, fmaxf(-1.f, rintf(v.z * inv))); o.z = f2bf(t);
  t = fminf(1.f, fmaxf(-1.f, rintf(v.w * inv))); o.w = f2bf(t);
  ((ushort4*)wt)[tid] = o;
}

// ---------------- 256x256 GEMM (r8 schedule, 32x32x16 MFMA) ----------------
// BM=BN=256, BK=64, 8 waves (2Mx4N), 512 thr, LDS 128KB dbuf, XOR swizzle (0 conflicts),
// counted vmcnt(4)/tile, 2 barriers/tile, K-loop x2 unrolled (compile-time buffer selects).
// MFMA = 32x32x16 bf16 (4061 vs 3377 FLOP/cyc/CU; half the instruction count).
// Fragment: lane l: row/col = l&31, k-chunk = (l>>5)*8 elems; per-phase banks distinct
// under the same byte^=(row&7)<<4 swizzle. C/D map: col=lane&31,
// row=(reg&3)+8*(reg>>2)+4*(lane>>5)  [m74/m101 verified].

#define VMCNT(n) asm volatile("s_waitcnt vmcnt(" #n ")" ::: "memory")
#define FENCE    asm volatile("" ::: "memory")
#define BARRIER  do { FENCE; __builtin_amdgcn_s_barrier(); FENCE; } while (0)

// A-quadrant read: 2 mb x 4 ks = 8 x ds_read_b128
#define READ_A(base, mh, dst)                                                                   \
  do {                                                                                          \
    _Pragma("unroll") for (int mb2 = 0; mb2 < 2; ++mb2)                                         \
      _Pragma("unroll") for (int ks = 0; ks < 4; ++ks)                                          \
        dst[mb2][ks] = *(const bf16x8*)((base) +                                                \
            (wr * 128 + ((mh) * 2 + mb2) * 32 + l31) * 128 +                                    \
            ((ks * 32 + lh1 * 16) ^ swzB));                                                     \
  } while (0)

// B-quadrant read: 4 ks = 4 x ds_read_b128
#define READ_B(base, nh, dst)                                                                   \
  do {                                                                                          \
    _Pragma("unroll") for (int ks = 0; ks < 4; ++ks)                                            \
      dst[ks] = *(const bf16x8*)((base) +                                                       \
          (wc * 64 + (nh) * 32 + l31) * 128 +                                                   \
          ((ks * 32 + lh1 * 16) ^ swzB));                                                       \
  } while (0)

// quadrant MFMA: 2 acc blocks x 4 k-steps = 8 x mfma_32x32x16
#define MFMA_Q(mh, nh, ar, br)                                                                  \
  do {                                                                                          \
    __builtin_amdgcn_s_setprio(1);                                                              \
    _Pragma("unroll") for (int ks = 0; ks < 4; ++ks)                                            \
      _Pragma("unroll") for (int mb2 = 0; mb2 < 2; ++mb2)                                       \
        acc[(mh) * 2 + mb2][nh] = __builtin_amdgcn_mfma_f32_32x32x16_bf16(                      \
            ar[mb2][ks], br[ks], acc[(mh) * 2 + mb2][nh], 0, 0, 0);                             \
    __builtin_amdgcn_s_setprio(0);                                                              \
  } while (0)

// stage half-tiles: linear LDS dest (gload_lds requirement), inverse-swizzled global source
#define SA(bufsel, r) gload_lds16(Ag + offA[r] + ktA, ldsb + (bufsel) * 65536 + tid * 16 + (r) * 8192)
#define SB(bufsel, r) gload_lds16(Bg + offB[r] + ktB, ldsb + (bufsel) * 65536 + 32768 + tid * 16 + (r) * 8192)

// one K-tile body (r8 schedule). CURSEL = this tile's buffer, NXTSEL = other buffer.
#define TILE_BODY(CURSEL, NXTSEL, t)                                                            \
  do {                                                                                          \
    const char* curA = ldsb + (CURSEL) * 65536;                                                 \
    const char* curB = curA + 32768;                                                            \
    READ_A(curA, 0, a0);                                                                        \
    READ_B(curB, 0, b0);                                                                        \
    if ((t) < NT - 1) { SA(NXTSEL, 0); SA(NXTSEL, 1); }                                         \
    MFMA_Q(0, 0, a0, b0);                                                                       \
    READ_B(curB, 1, b1);                                                                        \
    if ((t) < NT - 1) { SA(NXTSEL, 2); SA(NXTSEL, 3); ktA += 128; }                             \
    MFMA_Q(0, 1, a0, b1);                                                                       \
    BARRIER; /* all waves consumed B[t] (b0,b1 in regs) -> B-region may be overwritten */       \
    READ_A(curA, 1, a1);                                                                        \
    if ((t) < NT - 2) { SB(CURSEL, 0); SB(CURSEL, 1); }                                         \
    MFMA_Q(1, 0, a1, b0);                                                                       \
    if ((t) < NT - 2) {                                                                         \
      SB(CURSEL, 2); SB(CURSEL, 3); ktB += 128;                                                 \
      VMCNT(4); /* oldest [T+1.B, T+1.A] land; newest 4 (T+2.B) stay in flight */               \
    } else {                                                                                    \
      VMCNT(0);                                                                                 \
    }                                                                                           \
    MFMA_Q(1, 1, a1, b1);                                                                       \
    BARRIER; /* tile end: A[t] consumed; T(t+1) fully in LDS */                                 \
  } while (0)

__global__ void __launch_bounds__(512, 2)
gemm_bt(const unsigned short* __restrict__ A, const unsigned short* __restrict__ Bt,
        const float* __restrict__ bias, const float* __restrict__ scale_p,
        float* __restrict__ out) {
  __shared__ __align__(16) char lds_raw[131072];
  char* ldsb = (char*)lds_raw;

  const int tid = threadIdx.x;                 // 0..511
  const int lane = tid & 63;
  const int wid = tid >> 6;                    // 0..7
  const int wr = wid >> 2;                     // 0..1
  const int wc = wid & 3;                      // 0..3
  const int l31 = lane & 31, lh1 = lane >> 5;

  // 3-bit read swizzle: byte ^= (row&7)<<4 ; row&7 == l31&7 (rows land on l31)
  const int swzB = (l31 & 7) << 4;

  // XCD-aware swizzle: 256 blocks, 8 XCDs x 32-chunk; bm-major inside chunk
  const int bid = blockIdx.x;
  const int swz = (bid & 7) * 32 + (bid >> 3);
  const int bm = swz >> 3;                     // 0..31
  const int bn = swz & 7;                      // 0..7
  const int m0 = bm << 8, n0 = bn << 8;

  // staging: thread stages LDS row srow+r*64, colbyte (tid&7)*16 (linear dest);
  // global source column inverse-swizzled so swizzled ds_reads see linear data.
  const int srow = tid >> 3;                                          // 0..63
  const int scol = (((tid & 7) ^ ((tid >> 3) & 7)) << 4);             // cb ^ (row&7)<<4
  const char* Ag = (const char*)A;
  const char* Bg = (const char*)Bt;
  uint32_t offA[4], offB[4];
#pragma unroll
  for (int r = 0; r < 4; ++r) {
    offA[r] = (uint32_t)(m0 + srow + r * 64) * (K_DIM * 2) + scol;
    offB[r] = (uint32_t)(n0 + srow + r * 64) * (K_DIM * 2) + scol;
  }
  uint32_t ktA = 0, ktB = 0;   // byte offset along K of next tile to stage (BK*2 = 128)

  f32x16 acc[4][2];
  {
    f32x16 z;
#pragma unroll
    for (int e = 0; e < 16; ++e) z[e] = 0.f;
#pragma unroll
    for (int m = 0; m < 4; ++m)
#pragma unroll
      for (int n = 0; n < 2; ++n) acc[m][n] = z;
  }

  // ---- prologue: stage T0 (A+B -> buf0), T1.B -> buf1; drain T0, keep T1.B in flight
  SA(0, 0); SA(0, 1); SA(0, 2); SA(0, 3);
  SB(0, 0); SB(0, 1); SB(0, 2); SB(0, 3);
  ktB = 128;
  SB(1, 0); SB(1, 1); SB(1, 2); SB(1, 3);
  ktA = 128; ktB = 256;
  VMCNT(4);
  BARRIER;

  bf16x8 a0[2][4], a1[2][4], b0[4], b1[4];

  for (int it = 0; it < NT / 2; ++it) {
    const int t0 = 2 * it;
    TILE_BODY(0, 1, t0);       // even tile: compute buf0, stage A->buf1, B(t+2)->buf0
    TILE_BODY(1, 0, t0 + 1);   // odd tile:  compute buf1, stage A->buf0, B(t+2)->buf1
  }

  // ---- epilogue: 32x32 C/D map col=lane&31, row=(reg&3)+8*(reg>>2)+4*(lane>>5)
  const float scale = scale_p[0];
#pragma unroll
  for (int nb = 0; nb < 2; ++nb) {
    const int col = n0 + wc * 64 + nb * 32 + l31;
    const float bv = bias[col];
#pragma unroll
    for (int mb = 0; mb < 4; ++mb) {
      const int rbase = m0 + wr * 128 + mb * 32 + 4 * lh1;
      float* op = out + (size_t)rbase * N_DIM + col;
#pragma unroll
      for (int reg = 0; reg < 16; ++reg) {
        const int roff = (reg & 3) + 8 * (reg >> 2);
        op[(size_t)roff * N_DIM] = acc[mb][nb][reg] * scale + bv;
      }
    }
  }
}

extern "C" void kernel_launch(void* const* d_in, const int* in_sizes, int n_in,
                              void* d_out, int out_size, void* d_ws, size_t ws_size,
                              hipStream_t stream) {
  (void)in_sizes; (void)n_in; (void)out_size; (void)ws_size;
  const float* x    = (const float*)d_in[0];   // [4][2048][2048] f32
  const float* w    = (const float*)d_in[1];   // [2048][2048] f32
  const float* bias = (const float*)d_in[2];   // [2048] f32
  float* out = (float*)d_out;                  // [4][2048][2048] f32

  float* partials = (float*)d_ws;                              // 1024 f32
  float* scale_slot = partials + 1024;                         // 1 f32
  unsigned short* wt = (unsigned short*)((char*)d_ws + 8192);  // 8 MB bf16 W_t
  unsigned short* xb = (unsigned short*)((char*)d_ws + 8192 + (size_t)N_DIM * K_DIM * 2);  // 32 MB

  cvt_x_absum<<<17408, 256, 0, stream>>>(x, xb, w, partials);
  quant_w<<<4096, 256, 0, stream>>>(w, partials, wt, scale_slot);
  gemm_bt<<<256, 512, 0, stream>>>(xb, wt, bias, scale_slot, out);
}